// Round 4
// baseline (105.135 us; speedup 1.0000x reference)
//
#include <hip/hip_runtime.h>
#include <math.h>

// PhysQuadModel rollout, fully parallel over (env, time).
// Round-4: split per-env prologue into a tiny prep kernel (1 thread/env) that
// writes 36 consts/env to d_ws; the emit kernel keeps them wave-uniform in
// SGPRs (readfirstlane), recomputes cheap HW trig instead of caching partial
// sums (cuts VGPR), and uses precomputed quat-power coefficients A so the
// per-row quaternion is 8 FMAs.

namespace {
constexpr float DT_  = 0.01f;
constexpr float G_   = 9.81f;
constexpr float TTW_ = 1.8f;
constexpr float M_   = 0.033f;
constexpr float KT_  = 3.72e-08f;
constexpr float EPS_ = 1e-6f;
constexpr float INV2PI = 0.15915494309189535f;
constexpr float PI_F   = 3.14159265358979f;
constexpr float PIH_F  = 1.57079632679490f;
constexpr int   CF     = 36;   // floats per env in d_ws
}

__device__ __forceinline__ void fsincos(float x, float& s, float& c) {
#if __has_builtin(__builtin_amdgcn_sinf) && __has_builtin(__builtin_amdgcn_cosf)
    float r = x * INV2PI;
    r = r - floorf(r);              // v_fract; v_sin/v_cos take revolutions
    s = __builtin_amdgcn_sinf(r);
    c = __builtin_amdgcn_cosf(r);
#else
    s = sinf(x); c = cosf(x);
#endif
}

__device__ __forceinline__ float frcp(float x) {
#if __has_builtin(__builtin_amdgcn_rcpf)
    return __builtin_amdgcn_rcpf(x);
#else
    return 1.0f / x;
#endif
}

__device__ __forceinline__ float rfl(float x) {
    return __int_as_float(__builtin_amdgcn_readfirstlane(__float_as_int(x)));
}

// atan2(nv, qw) for nv >= 0 with nv^2 + qw^2 == 1 (unit circle). No division.
__device__ __forceinline__ float half_atan2_unit(float nv, float qw) {
    float aw = fabsf(qw);
    float m  = fminf(nv, aw);
    float t  = m * m;
    float p  = 0.01155185f;
    p = fmaf(p, t, 0.01396482f);
    p = fmaf(p, t, 0.01735277f);
    p = fmaf(p, t, 0.02237216f);
    p = fmaf(p, t, 0.03038194f);
    p = fmaf(p, t, 0.04464286f);
    p = fmaf(p, t, 0.075f);
    p = fmaf(p, t, 0.16666667f);
    p = fmaf(p, t, 1.0f);
    p = p * m;                                  // asin(m)
    return (nv < aw) ? ((qw >= 0.0f) ? p : (PI_F - p))
                     : (PIH_F - copysignf(p, qw));
}

__device__ __forceinline__ float4 qmul(float4 p, float4 q) {
    return make_float4(
        p.w*q.x + q.w*p.x + (p.y*q.z - p.z*q.y),
        p.w*q.y + q.w*p.y + (p.z*q.x - p.x*q.z),
        p.w*q.z + q.w*p.z + (p.x*q.y - p.y*q.x),
        p.w*q.w - (p.x*q.x + p.y*q.y + p.z*q.z));
}

__device__ __forceinline__ float4 qnormalize(float4 q) {
    float inv = 1.0f / sqrtf(q.x*q.x + q.y*q.y + q.z*q.z + q.w*q.w);
    return make_float4(q.x*inv, q.y*inv, q.z*inv, q.w*inv);
}

__device__ __forceinline__ float4 qmul_pure(float4 n, float wx, float wy, float wz) {
    return make_float4(
        n.w*wx + (n.y*wz - n.z*wy),
        n.w*wy + (n.z*wx - n.x*wz),
        n.w*wz + (n.x*wy - n.y*wx),
        -(n.x*wx + n.y*wy + n.z*wz));
}

// ---------------------------------------------------------------------------
// Kernel A: per-env prologue (1 thread per env), writes 36 consts to ws.
// ---------------------------------------------------------------------------
__global__ __launch_bounds__(256)
void quad_prep_kernel(const float* __restrict__ x0, float* __restrict__ ws, int B)
{
    int env = blockIdx.x * 256 + threadIdx.x;
    if (env >= B) return;

    const float4* xs4 = (const float4*)(x0 + (size_t)env * 12);
    float4 xA = xs4[0], xB = xs4[1], xC = xs4[2];
    const float px0 = xA.x, py0 = xA.y, pz0 = xA.z;
    const float vx0 = xA.w, vy0 = xB.x, vz0 = xB.y;
    const float rx  = xB.z, ry  = xB.w, rz  = xC.x;
    const float ox  = xC.y, oy  = xC.z, oz  = xC.w;

    float ang = sqrtf(rx*rx + ry*ry + rz*rz);
    float hf  = 0.5f * ang;
    float sh, ch;
    sincosf(hf, &sh, &ch);
    float so = (ang < EPS_) ? (0.5f - ang*ang*(1.0f/48.0f)) : (sh / ang);
    float4 q0 = make_float4(rx*so, ry*so, rz*so, ch);

    const float dt = DT_, dt4 = 0.25f*dt, dt2 = 0.5f*dt, dt12 = dt*(1.0f/12.0f);
    float4 n2 = qnormalize(make_float4(dt4*ox, dt4*oy, dt4*oz, 1.0f));
    float4 m2 = qmul_pure(n2, ox, oy, oz);
    float4 n3 = qnormalize(make_float4(dt4*m2.x, dt4*m2.y, dt4*m2.z, 1.0f + dt4*m2.w));
    float4 m3 = qmul_pure(n3, ox, oy, oz);
    float4 n4 = qnormalize(make_float4(dt2*m3.x, dt2*m3.y, dt2*m3.z, 1.0f + dt2*m3.w));
    float4 m4 = qmul_pure(n4, ox, oy, oz);
    float4 P  = qnormalize(make_float4(
        dt12*(ox + 2.0f*m2.x + 2.0f*m3.x + m4.x),
        dt12*(oy + 2.0f*m2.y + 2.0f*m3.y + m4.y),
        dt12*(oz + 2.0f*m2.z + 2.0f*m3.z + m4.z),
        1.0f + dt12*(2.0f*m2.w + 2.0f*m3.w + m4.w)));

    #define COL3X(q) (2.0f*((q).x*(q).z + (q).w*(q).y))
    #define COL3Y(q) (2.0f*((q).y*(q).z - (q).w*(q).x))
    #define COL3Z(q) (1.0f - 2.0f*((q).x*(q).x + (q).y*(q).y))
    float c2x = COL3X(n2), c2y = COL3Y(n2), c2z = COL3Z(n2);
    float c3x = COL3X(n3), c3y = COL3Y(n3), c3z = COL3Z(n3);
    float c4x = COL3X(n4), c4y = COL3Y(n4), c4z = COL3Z(n4);
    float Cvx = 2.0f*(c2x + c3x) + c4x;
    float Cvy = 2.0f*(c2y + c3y) + c4y;
    float Cvz = 1.0f + 2.0f*(c2z + c3z) + c4z;
    float Cpx = c2x + c3x;
    float Cpy = c2y + c3y;
    float Cpz = 1.0f + c2z + c3z;

    float un   = sqrtf(P.x*P.x + P.y*P.y + P.z*P.z);
    float phih = atan2f(un, P.w);
    float ux, uy, uz;
    if (un > 1e-20f) { float iu = 1.0f/un; ux = P.x*iu; uy = P.y*iu; uz = P.z*iu; }
    else             { ux = 0.0f; uy = 0.0f; uz = 1.0f; }

    float dv = ux*Cvx + uy*Cvy + uz*Cvz;
    float vpx = dv*ux, vpy = dv*uy, vpz = dv*uz;
    float vex = Cvx - vpx, vey = Cvy - vpy, vez = Cvz - vpz;
    float vcx = uy*Cvz - uz*Cvy, vcy = uz*Cvx - ux*Cvz, vcz = ux*Cvy - uy*Cvx;
    float dp = ux*Cpx + uy*Cpy + uz*Cpz;
    float ppx = dp*ux, ppy = dp*uy, ppz = dp*uz;
    float pex = Cpx - ppx, pey = Cpy - ppy, pez = Cpz - ppz;
    float pcx = uy*Cpz - uz*Cpy, pcy = uz*Cpx - ux*Cpz, pcz = ux*Cpy - uy*Cpx;

    float qx = q0.x, qy = q0.y, qz = q0.z, qw = q0.w;
    float r00 = 1.0f - 2.0f*(qy*qy + qz*qz), r01 = 2.0f*(qx*qy - qw*qz), r02 = 2.0f*(qx*qz + qw*qy);
    float r10 = 2.0f*(qx*qy + qw*qz), r11 = 1.0f - 2.0f*(qx*qx + qz*qz), r12 = 2.0f*(qy*qz - qw*qx);
    float r20 = 2.0f*(qx*qz - qw*qy), r21 = 2.0f*(qy*qz + qw*qx), r22 = 1.0f - 2.0f*(qx*qx + qy*qy);
    #define ROT_X(X,Y,Z) (r00*(X) + r01*(Y) + r02*(Z))
    #define ROT_Y(X,Y,Z) (r10*(X) + r11*(Y) + r12*(Z))
    #define ROT_Z(X,Y,Z) (r20*(X) + r21*(Y) + r22*(Z))
    float Gvpx = ROT_X(vpx,vpy,vpz), Gvpy = ROT_Y(vpx,vpy,vpz), Gvpz = ROT_Z(vpx,vpy,vpz);
    float Gvex = ROT_X(vex,vey,vez), Gvey = ROT_Y(vex,vey,vez), Gvez = ROT_Z(vex,vey,vez);
    float Gvcx = ROT_X(vcx,vcy,vcz), Gvcy = ROT_Y(vcx,vcy,vcz), Gvcz = ROT_Z(vcx,vcy,vcz);
    float Gppx = ROT_X(ppx,ppy,ppz), Gppy = ROT_Y(ppx,ppy,ppz), Gppz = ROT_Z(ppx,ppy,ppz);
    float Gpex = ROT_X(pex,pey,pez), Gpey = ROT_Y(pex,pey,pez), Gpez = ROT_Z(pex,pey,pez);
    float Gpcx = ROT_X(pcx,pcy,pcz), Gpcy = ROT_Y(pcx,pcy,pcz), Gpcz = ROT_Z(pcx,pcy,pcz);

    // quat-power coefficients: qt = st*A + ct*q0 (componentwise), Aw = -(q0.u)
    float Ax = q0.w*ux + q0.y*uz - q0.z*uy;
    float Ay = q0.w*uy + q0.z*ux - q0.x*uz;
    float Az = q0.w*uz + q0.x*uy - q0.y*ux;
    float Aw = -(q0.x*ux + q0.y*uy + q0.z*uz);

    float4* w4 = (float4*)(ws + (size_t)env * CF);
    w4[0] = make_float4(Gvpx, Gvpy, Gvpz, Gvex);
    w4[1] = make_float4(Gvey, Gvez, Gvcx, Gvcy);
    w4[2] = make_float4(Gvcz, Gppx, Gppy, Gppz);
    w4[3] = make_float4(Gpex, Gpey, Gpez, Gpcx);
    w4[4] = make_float4(Gpcy, Gpcz, Ax,   Ay);
    w4[5] = make_float4(Az,   Aw,   phih, q0.x);
    w4[6] = make_float4(q0.y, q0.z, q0.w, vx0);
    w4[7] = make_float4(vy0,  vz0,  px0,  py0);
    w4[8] = make_float4(pz0,  ox,   oy,   oz);
}

// ---------------------------------------------------------------------------
// Kernel B: scan + emit. One wave per env, 4 rows/lane, consts in SGPRs.
// ---------------------------------------------------------------------------
__global__ __launch_bounds__(128, 8)
void quad_emit_kernel(const float4* __restrict__ u_seq,
                      const float* __restrict__ ws,
                      float* __restrict__ out,
                      int B, int N)
{
    const int wave = threadIdx.x >> 6;
    const int lane = threadIdx.x & 63;
    const int env  = blockIdx.x * 2 + wave;
    if (env >= B) return;
    const int k0 = lane * 4;

    // issue u loads first; latency overlaps the const-fetch + SGPR move phase
    const float4* __restrict__ up = u_seq + (size_t)env * N + k0;
    float4 u0 = (k0     < N) ? up[0] : make_float4(0.f,0.f,0.f,0.f);
    float4 u1 = (k0 + 1 < N) ? up[1] : make_float4(0.f,0.f,0.f,0.f);
    float4 u2 = (k0 + 2 < N) ? up[2] : make_float4(0.f,0.f,0.f,0.f);
    float4 u3 = (k0 + 3 < N) ? up[3] : make_float4(0.f,0.f,0.f,0.f);

    const float* __restrict__ c =
        ws + (size_t)__builtin_amdgcn_readfirstlane(env) * CF;
    float Gvpx = rfl(c[0]),  Gvpy = rfl(c[1]),  Gvpz = rfl(c[2]);
    float Gvex = rfl(c[3]),  Gvey = rfl(c[4]),  Gvez = rfl(c[5]);
    float Gvcx = rfl(c[6]),  Gvcy = rfl(c[7]),  Gvcz = rfl(c[8]);
    float Gppx = rfl(c[9]),  Gppy = rfl(c[10]), Gppz = rfl(c[11]);
    float Gpex = rfl(c[12]), Gpey = rfl(c[13]), Gpez = rfl(c[14]);
    float Gpcx = rfl(c[15]), Gpcy = rfl(c[16]), Gpcz = rfl(c[17]);
    __builtin_amdgcn_sched_barrier(0);   // keep the two const batches separate (VGPR peak)
    float Ax = rfl(c[18]), Ay = rfl(c[19]), Az = rfl(c[20]), Aw = rfl(c[21]);
    float phih = rfl(c[22]);
    float q0x = rfl(c[23]), q0y = rfl(c[24]), q0z = rfl(c[25]), q0w = rfl(c[26]);
    float vx0 = rfl(c[27]), vy0 = rfl(c[28]), vz0 = rfl(c[29]);
    float px0 = rfl(c[30]), py0 = rfl(c[31]), pz0 = rfl(c[32]);
    float ox  = rfl(c[33]), oy  = rfl(c[34]), oz  = rfl(c[35]);
    const float theta = phih + phih;

    const float dt      = DT_;
    const float invTMAX = 1.0f / (TTW_ * M_ * G_);
    const float TACC    = TTW_ * G_;
    const float dt6     = dt * (1.0f/6.0f);
    const float dt26    = dt * dt * (1.0f/6.0f);
    const float gdt     = dt * G_;
    const float hgdt2   = 0.5f * dt * dt * G_;
    const float dtvx = dt*vx0, dtvy = dt*vy0, dtvz = dt*vz0;

    // ---- phase 1: per-step thrust + trig, 6 running sums ----
    float sa=0.f, sb=0.f, sc=0.f, sA=0.f, sB=0.f, sC=0.f;
    float Ta0, Ta1, Ta2, Ta3;
    #define PH1(J, UU, TAJ) { \
        float kf = (float)(k0 + (J)); \
        float w2 = UU.x*UU.x + UU.y*UU.y + UU.z*UU.z + UU.w*UU.w; \
        float Tn = fminf(fmaxf(KT_*w2*invTMAX, 0.0f), 1.0f); \
        TAJ = Tn * TACC; \
        float sn, cs; fsincos(theta * kf, sn, cs); \
        float kTa = kf * TAJ; \
        sa += TAJ; sb = fmaf(TAJ, cs, sb); sc = fmaf(TAJ, sn, sc); \
        sA += kTa; sB = fmaf(kTa, cs, sB); sC = fmaf(kTa, sn, sC); }
    PH1(0, u0, Ta0)
    PH1(1, u1, Ta1)
    PH1(2, u2, Ta2)
    PH1(3, u3, Ta3)
    #undef PH1

    // ---- wave-wide inclusive scan of lane totals ----
    float ta = sa, tb = sb, tc = sc, tA = sA, tB = sB, tC = sC;
    #pragma unroll
    for (int d = 1; d < 64; d <<= 1) {
        float xa = __shfl_up(ta, d), xb = __shfl_up(tb, d), xc = __shfl_up(tc, d);
        float xA = __shfl_up(tA, d), xB = __shfl_up(tB, d), xC = __shfl_up(tC, d);
        if (lane >= d) { ta += xa; tb += xb; tc += xc; tA += xA; tB += xB; tC += xC; }
    }
    // exclusive bases -> running accumulators
    float aa = ta - sa, ab = tb - sb, ac = tc - sc;
    float aA = tA - sA, aB = tB - sB, aC = tC - sC;

    // ---- emit 4 rows, recomputing cheap trig; accumulators advance per row ----
    float* __restrict__ op = out + ((size_t)env * N + k0) * 12;
    #define EMIT(J, TAJ) if (k0 + (J) < N) { \
        float kf = (float)(k0 + (J)); \
        float sn, cs; fsincos(theta * kf, sn, cs); \
        float kTa = kf * (TAJ); \
        aa += (TAJ); ab = fmaf((TAJ), cs, ab); ac = fmaf((TAJ), sn, ac); \
        aA += kTa;   aB = fmaf(kTa, cs, aB);  aC = fmaf(kTa, sn, aC); \
        float tf = kf + 1.0f; \
        float Wa = fmaf(kf, aa, -aA), Wb = fmaf(kf, ab, -aB), Wc = fmaf(kf, ac, -aC); \
        float rvx = fmaf(aa, Gvpx, fmaf(ab, Gvex, ac*Gvcx)); \
        float rvy = fmaf(aa, Gvpy, fmaf(ab, Gvey, ac*Gvcy)); \
        float rvz = fmaf(aa, Gvpz, fmaf(ab, Gvez, ac*Gvcz)); \
        float rpx = fmaf(Wa, Gvpx, fmaf(Wb, Gvex, fmaf(Wc, Gvcx, fmaf(aa, Gppx, fmaf(ab, Gpex, ac*Gpcx))))); \
        float rpy = fmaf(Wa, Gvpy, fmaf(Wb, Gvey, fmaf(Wc, Gvcy, fmaf(aa, Gppy, fmaf(ab, Gpey, ac*Gpcy))))); \
        float rpz = fmaf(Wa, Gvpz, fmaf(Wb, Gvez, fmaf(Wc, Gvcz, fmaf(aa, Gppz, fmaf(ab, Gpez, ac*Gpcz))))); \
        float velx = fmaf(dt6, rvx, vx0); \
        float vely = fmaf(dt6, rvy, vy0); \
        float velz = fmaf(dt6, rvz, vz0) - tf * gdt; \
        float posx = fmaf(tf, dtvx, fmaf(dt26, rpx, px0)); \
        float posy = fmaf(tf, dtvy, fmaf(dt26, rpy, py0)); \
        float posz = fmaf(tf, dtvz, fmaf(dt26, rpz, pz0)) - (tf*tf) * hgdt2; \
        float st, ct; fsincos(phih * tf, st, ct); \
        float qtx = fmaf(st, Ax, ct * q0x); \
        float qty = fmaf(st, Ay, ct * q0y); \
        float qtz = fmaf(st, Az, ct * q0z); \
        float qtw = fmaf(st, Aw, ct * q0w); \
        float nv  = sqrtf(fmaf(qtx, qtx, fmaf(qty, qty, qtz*qtz))); \
        float h   = half_atan2_unit(nv, qtw); \
        float scl = (h + h) * frcp(fmaxf(nv, 1e-12f)); \
        float4* o4 = (float4*)(op + (J) * 12); \
        o4[0] = make_float4(posx, posy, posz, velx); \
        o4[1] = make_float4(vely, velz, qtx*scl, qty*scl); \
        o4[2] = make_float4(qtz*scl, ox, oy, oz); }
    EMIT(0, Ta0)
    EMIT(1, Ta1)
    EMIT(2, Ta2)
    EMIT(3, Ta3)
    #undef EMIT
}

// ---------------------------------------------------------------------------
// Fallback: monolithic kernel (round-3, proven) if ws is too small.
// ---------------------------------------------------------------------------
__global__ __launch_bounds__(256)
void quad_mono_kernel(const float* __restrict__ x0,
                      const float4* __restrict__ u_seq,
                      float* __restrict__ out,
                      int B, int N)
{
    const int wave = threadIdx.x >> 6;
    const int lane = threadIdx.x & 63;
    const int env  = blockIdx.x * 4 + wave;
    if (env >= B) return;

    const float4* xs4 = (const float4*)(x0 + (size_t)env * 12);
    float4 xA = xs4[0], xB = xs4[1], xC = xs4[2];
    const float px0 = xA.x, py0 = xA.y, pz0 = xA.z;
    const float vx0 = xA.w, vy0 = xB.x, vz0 = xB.y;
    const float rx  = xB.z, ry  = xB.w, rz  = xC.x;
    const float ox  = xC.y, oy  = xC.z, oz  = xC.w;

    float ang = sqrtf(rx*rx + ry*ry + rz*rz);
    float hf  = 0.5f * ang;
    float sh, ch;
    sincosf(hf, &sh, &ch);
    float so = (ang < EPS_) ? (0.5f - ang*ang*(1.0f/48.0f)) : (sh / ang);
    float4 q0 = make_float4(rx*so, ry*so, rz*so, ch);

    const float dt = DT_, dt4 = 0.25f*dt, dt2 = 0.5f*dt, dt12 = dt*(1.0f/12.0f);
    float4 n2 = qnormalize(make_float4(dt4*ox, dt4*oy, dt4*oz, 1.0f));
    float4 m2 = qmul_pure(n2, ox, oy, oz);
    float4 n3 = qnormalize(make_float4(dt4*m2.x, dt4*m2.y, dt4*m2.z, 1.0f + dt4*m2.w));
    float4 m3 = qmul_pure(n3, ox, oy, oz);
    float4 n4 = qnormalize(make_float4(dt2*m3.x, dt2*m3.y, dt2*m3.z, 1.0f + dt2*m3.w));
    float4 m4 = qmul_pure(n4, ox, oy, oz);
    float4 P  = qnormalize(make_float4(
        dt12*(ox + 2.0f*m2.x + 2.0f*m3.x + m4.x),
        dt12*(oy + 2.0f*m2.y + 2.0f*m3.y + m4.y),
        dt12*(oz + 2.0f*m2.z + 2.0f*m3.z + m4.z),
        1.0f + dt12*(2.0f*m2.w + 2.0f*m3.w + m4.w)));

    float c2x = COL3X(n2), c2y = COL3Y(n2), c2z = COL3Z(n2);
    float c3x = COL3X(n3), c3y = COL3Y(n3), c3z = COL3Z(n3);
    float c4x = COL3X(n4), c4y = COL3Y(n4), c4z = COL3Z(n4);
    float Cvx = 2.0f*(c2x + c3x) + c4x;
    float Cvy = 2.0f*(c2y + c3y) + c4y;
    float Cvz = 1.0f + 2.0f*(c2z + c3z) + c4z;
    float Cpx = c2x + c3x;
    float Cpy = c2y + c3y;
    float Cpz = 1.0f + c2z + c3z;

    float un   = sqrtf(P.x*P.x + P.y*P.y + P.z*P.z);
    float phih = atan2f(un, P.w);
    float theta = 2.0f * phih;
    float ux, uy, uz;
    if (un > 1e-20f) { float iu = 1.0f/un; ux = P.x*iu; uy = P.y*iu; uz = P.z*iu; }
    else             { ux = 0.0f; uy = 0.0f; uz = 1.0f; }

    float dv = ux*Cvx + uy*Cvy + uz*Cvz;
    float vpx = dv*ux, vpy = dv*uy, vpz = dv*uz;
    float vex = Cvx - vpx, vey = Cvy - vpy, vez = Cvz - vpz;
    float vcx = uy*Cvz - uz*Cvy, vcy = uz*Cvx - ux*Cvz, vcz = ux*Cvy - uy*Cvx;
    float dp = ux*Cpx + uy*Cpy + uz*Cpz;
    float ppx = dp*ux, ppy = dp*uy, ppz = dp*uz;
    float pex = Cpx - ppx, pey = Cpy - ppy, pez = Cpz - ppz;
    float pcx = uy*Cpz - uz*Cpy, pcy = uz*Cpx - ux*Cpz, pcz = ux*Cpy - uy*Cpx;

    float qx = q0.x, qy = q0.y, qz = q0.z, qw = q0.w;
    float r00 = 1.0f - 2.0f*(qy*qy + qz*qz), r01 = 2.0f*(qx*qy - qw*qz), r02 = 2.0f*(qx*qz + qw*qy);
    float r10 = 2.0f*(qx*qy + qw*qz), r11 = 1.0f - 2.0f*(qx*qx + qz*qz), r12 = 2.0f*(qy*qz - qw*qx);
    float r20 = 2.0f*(qx*qz - qw*qy), r21 = 2.0f*(qy*qz + qw*qx), r22 = 1.0f - 2.0f*(qx*qx + qy*qy);
    float Gvpx = ROT_X(vpx,vpy,vpz), Gvpy = ROT_Y(vpx,vpy,vpz), Gvpz = ROT_Z(vpx,vpy,vpz);
    float Gvex = ROT_X(vex,vey,vez), Gvey = ROT_Y(vex,vey,vez), Gvez = ROT_Z(vex,vey,vez);
    float Gvcx = ROT_X(vcx,vcy,vcz), Gvcy = ROT_Y(vcx,vcy,vcz), Gvcz = ROT_Z(vcx,vcy,vcz);
    float Gppx = ROT_X(ppx,ppy,ppz), Gppy = ROT_Y(ppx,ppy,ppz), Gppz = ROT_Z(ppx,ppy,ppz);
    float Gpex = ROT_X(pex,pey,pez), Gpey = ROT_Y(pex,pey,pez), Gpez = ROT_Z(pex,pey,pez);
    float Gpcx = ROT_X(pcx,pcy,pcz), Gpcy = ROT_Y(pcx,pcy,pcz), Gpcz = ROT_Z(pcx,pcy,pcz);

    const float invTMAX = 1.0f / (TTW_ * M_ * G_);
    const float TACC    = TTW_ * G_;

    const float4* __restrict__ up = u_seq + (size_t)env * N;
    float la[4], lb[4], lc[4], lA[4], lB[4], lC[4];
    float sa = 0.f, sb = 0.f, sc = 0.f, sA = 0.f, sB = 0.f, sC = 0.f;
    const int k0 = lane * 4;
    #pragma unroll
    for (int j = 0; j < 4; ++j) {
        int k = k0 + j;
        float Ta = 0.f, cs = 1.f, sn = 0.f, kf = (float)k;
        if (k < N) {
            float4 u = up[k];
            float w2 = u.x*u.x + u.y*u.y + u.z*u.z + u.w*u.w;
            float Tn = fminf(fmaxf(KT_*w2*invTMAX, 0.0f), 1.0f);
            Ta = Tn * TACC;
            fsincos(theta * kf, sn, cs);
        }
        sa += Ta;        sb += Ta*cs;     sc += Ta*sn;
        sA += kf*Ta;     sB += kf*Ta*cs;  sC += kf*Ta*sn;
        la[j] = sa; lb[j] = sb; lc[j] = sc;
        lA[j] = sA; lB[j] = sB; lC[j] = sC;
    }

    float ta = sa, tb = sb, tc = sc, tA = sA, tB = sB, tC = sC;
    #pragma unroll
    for (int d = 1; d < 64; d <<= 1) {
        float xa = __shfl_up(ta, d), xb = __shfl_up(tb, d), xc = __shfl_up(tc, d);
        float xA = __shfl_up(tA, d), xB = __shfl_up(tB, d), xC = __shfl_up(tC, d);
        if (lane >= d) { ta += xa; tb += xb; tc += xc; tA += xA; tB += xB; tC += xC; }
    }
    const float ba = ta - sa, bb = tb - sb, bc = tc - sc;
    const float bA = tA - sA, bB = tB - sB, bC = tC - sC;

    float* __restrict__ op = out + (size_t)env * N * 12;
    const float dt6  = dt * (1.0f/6.0f);
    const float dt26 = dt * dt * (1.0f/6.0f);
    #pragma unroll
    for (int j = 0; j < 4; ++j) {
        int k = k0 + j;
        if (k >= N) break;
        float Ea = ba + la[j], Eb = bb + lb[j], Ec = bc + lc[j];
        float EA = bA + lA[j], EB = bB + lB[j], EC = bC + lC[j];
        float tf = (float)(k + 1);
        float cw = tf - 1.0f;
        float Wa = cw*Ea - EA, Wb = cw*Eb - EB, Wc = cw*Ec - EC;

        float rvx = Gvpx*Ea + Gvex*Eb + Gvcx*Ec;
        float rvy = Gvpy*Ea + Gvey*Eb + Gvcy*Ec;
        float rvz = Gvpz*Ea + Gvez*Eb + Gvcz*Ec;
        float rpx = Gvpx*Wa + Gvex*Wb + Gvcx*Wc + Gppx*Ea + Gpex*Eb + Gpcx*Ec;
        float rpy = Gvpy*Wa + Gvey*Wb + Gvcy*Wc + Gppy*Ea + Gpey*Eb + Gpcy*Ec;
        float rpz = Gvpz*Wa + Gvez*Wb + Gvcz*Wc + Gppz*Ea + Gpez*Eb + Gpcz*Ec;

        float velx = vx0 + dt6*rvx;
        float vely = vy0 + dt6*rvy;
        float velz = vz0 + dt6*rvz - tf*dt*G_;
        float posx = px0 + tf*dt*vx0 + dt26*rpx;
        float posy = py0 + tf*dt*vy0 + dt26*rpy;
        float posz = pz0 + tf*dt*vz0 + dt26*rpz - 0.5f*tf*tf*dt*dt*G_;

        float st, ct;
        fsincos(phih * tf, st, ct);
        float4 Pt = make_float4(ux*st, uy*st, uz*st, ct);
        float4 qt = qmul(q0, Pt);

        float nv  = sqrtf(qt.x*qt.x + qt.y*qt.y + qt.z*qt.z);
        float h   = half_atan2_unit(nv, qt.w);
        float scl = 2.0f * h / fmaxf(nv, 1e-12f);

        float4* o4 = (float4*)(op + (size_t)k * 12);
        o4[0] = make_float4(posx, posy, posz, velx);
        o4[1] = make_float4(vely, velz, qt.x*scl, qt.y*scl);
        o4[2] = make_float4(qt.z*scl, ox, oy, oz);
    }
}

extern "C" void kernel_launch(void* const* d_in, const int* in_sizes, int n_in,
                              void* d_out, int out_size, void* d_ws, size_t ws_size,
                              hipStream_t stream) {
    const float*  x0    = (const float*)d_in[0];
    const float4* u_seq = (const float4*)d_in[1];
    float* out = (float*)d_out;
    int B = in_sizes[0] / 12;
    int N = in_sizes[1] / (B * 4);
    size_t need = (size_t)B * CF * sizeof(float);
    if (ws_size >= need) {
        float* ws = (float*)d_ws;
        hipLaunchKernelGGL(quad_prep_kernel, dim3((B + 255) / 256), dim3(256), 0, stream,
                           x0, ws, B);
        hipLaunchKernelGGL(quad_emit_kernel, dim3((B + 1) / 2), dim3(128), 0, stream,
                           u_seq, ws, out, B, N);
    } else {
        hipLaunchKernelGGL(quad_mono_kernel, dim3((B + 3) / 4), dim3(256), 0, stream,
                           x0, u_seq, out, B, N);
    }
}

// Round 5
// 74.627 us; speedup vs baseline: 1.4088x; 1.4088x over previous
//
#include <hip/hip_runtime.h>
#include <math.h>

// PhysQuadModel rollout, fully parallel over (env, time).
// Round-5: stores were the bottleneck (192B-stride 16B scatters, 2.4 TB/s vs
// 7 TB/s fill). Emit kernel now stages each wave's 128-row half-tile in
// wave-private LDS (chunk-rotation swizzle, aligned b128 both ways) and
// flushes with fully-coalesced dwordx4 stores. Two 128-step passes with scan
// carry keep LDS at 6 KB/wave.

namespace {
constexpr float DT_  = 0.01f;
constexpr float G_   = 9.81f;
constexpr float TTW_ = 1.8f;
constexpr float M_   = 0.033f;
constexpr float KT_  = 3.72e-08f;
constexpr float EPS_ = 1e-6f;
constexpr float INV2PI = 0.15915494309189535f;
constexpr float PI_F   = 3.14159265358979f;
constexpr float PIH_F  = 1.57079632679490f;
constexpr int   CF     = 36;   // floats per env in d_ws
}

__device__ __forceinline__ void fsincos(float x, float& s, float& c) {
#if __has_builtin(__builtin_amdgcn_sinf) && __has_builtin(__builtin_amdgcn_cosf)
    float r = x * INV2PI;
    r = r - floorf(r);              // v_fract; v_sin/v_cos take revolutions
    s = __builtin_amdgcn_sinf(r);
    c = __builtin_amdgcn_cosf(r);
#else
    s = sinf(x); c = cosf(x);
#endif
}

__device__ __forceinline__ float frcp(float x) {
#if __has_builtin(__builtin_amdgcn_rcpf)
    return __builtin_amdgcn_rcpf(x);
#else
    return 1.0f / x;
#endif
}

__device__ __forceinline__ float rfl(float x) {
    return __int_as_float(__builtin_amdgcn_readfirstlane(__float_as_int(x)));
}

// atan2(nv, qw) for nv >= 0 with nv^2 + qw^2 == 1 (unit circle). No division.
__device__ __forceinline__ float half_atan2_unit(float nv, float qw) {
    float aw = fabsf(qw);
    float m  = fminf(nv, aw);
    float t  = m * m;
    float p  = 0.01155185f;
    p = fmaf(p, t, 0.01396482f);
    p = fmaf(p, t, 0.01735277f);
    p = fmaf(p, t, 0.02237216f);
    p = fmaf(p, t, 0.03038194f);
    p = fmaf(p, t, 0.04464286f);
    p = fmaf(p, t, 0.075f);
    p = fmaf(p, t, 0.16666667f);
    p = fmaf(p, t, 1.0f);
    p = p * m;                                  // asin(m)
    return (nv < aw) ? ((qw >= 0.0f) ? p : (PI_F - p))
                     : (PIH_F - copysignf(p, qw));
}

__device__ __forceinline__ float4 qmul(float4 p, float4 q) {
    return make_float4(
        p.w*q.x + q.w*p.x + (p.y*q.z - p.z*q.y),
        p.w*q.y + q.w*p.y + (p.z*q.x - p.x*q.z),
        p.w*q.z + q.w*p.z + (p.x*q.y - p.y*q.x),
        p.w*q.w - (p.x*q.x + p.y*q.y + p.z*q.z));
}

__device__ __forceinline__ float4 qnormalize(float4 q) {
    float inv = 1.0f / sqrtf(q.x*q.x + q.y*q.y + q.z*q.z + q.w*q.w);
    return make_float4(q.x*inv, q.y*inv, q.z*inv, q.w*inv);
}

__device__ __forceinline__ float4 qmul_pure(float4 n, float wx, float wy, float wz) {
    return make_float4(
        n.w*wx + (n.y*wz - n.z*wy),
        n.w*wy + (n.z*wx - n.x*wz),
        n.w*wz + (n.x*wy - n.y*wx),
        -(n.x*wx + n.y*wy + n.z*wz));
}

// ---------------------------------------------------------------------------
// Kernel A: per-env prologue (1 thread per env), writes 36 consts to ws.
// ---------------------------------------------------------------------------
__global__ __launch_bounds__(256)
void quad_prep_kernel(const float* __restrict__ x0, float* __restrict__ ws, int B)
{
    int env = blockIdx.x * 256 + threadIdx.x;
    if (env >= B) return;

    const float4* xs4 = (const float4*)(x0 + (size_t)env * 12);
    float4 xA = xs4[0], xB = xs4[1], xC = xs4[2];
    const float px0 = xA.x, py0 = xA.y, pz0 = xA.z;
    const float vx0 = xA.w, vy0 = xB.x, vz0 = xB.y;
    const float rx  = xB.z, ry  = xB.w, rz  = xC.x;
    const float ox  = xC.y, oy  = xC.z, oz  = xC.w;

    float ang = sqrtf(rx*rx + ry*ry + rz*rz);
    float hf  = 0.5f * ang;
    float sh, ch;
    sincosf(hf, &sh, &ch);
    float so = (ang < EPS_) ? (0.5f - ang*ang*(1.0f/48.0f)) : (sh / ang);
    float4 q0 = make_float4(rx*so, ry*so, rz*so, ch);

    const float dt = DT_, dt4 = 0.25f*dt, dt2 = 0.5f*dt, dt12 = dt*(1.0f/12.0f);
    float4 n2 = qnormalize(make_float4(dt4*ox, dt4*oy, dt4*oz, 1.0f));
    float4 m2 = qmul_pure(n2, ox, oy, oz);
    float4 n3 = qnormalize(make_float4(dt4*m2.x, dt4*m2.y, dt4*m2.z, 1.0f + dt4*m2.w));
    float4 m3 = qmul_pure(n3, ox, oy, oz);
    float4 n4 = qnormalize(make_float4(dt2*m3.x, dt2*m3.y, dt2*m3.z, 1.0f + dt2*m3.w));
    float4 m4 = qmul_pure(n4, ox, oy, oz);
    float4 P  = qnormalize(make_float4(
        dt12*(ox + 2.0f*m2.x + 2.0f*m3.x + m4.x),
        dt12*(oy + 2.0f*m2.y + 2.0f*m3.y + m4.y),
        dt12*(oz + 2.0f*m2.z + 2.0f*m3.z + m4.z),
        1.0f + dt12*(2.0f*m2.w + 2.0f*m3.w + m4.w)));

    #define COL3X(q) (2.0f*((q).x*(q).z + (q).w*(q).y))
    #define COL3Y(q) (2.0f*((q).y*(q).z - (q).w*(q).x))
    #define COL3Z(q) (1.0f - 2.0f*((q).x*(q).x + (q).y*(q).y))
    float c2x = COL3X(n2), c2y = COL3Y(n2), c2z = COL3Z(n2);
    float c3x = COL3X(n3), c3y = COL3Y(n3), c3z = COL3Z(n3);
    float c4x = COL3X(n4), c4y = COL3Y(n4), c4z = COL3Z(n4);
    float Cvx = 2.0f*(c2x + c3x) + c4x;
    float Cvy = 2.0f*(c2y + c3y) + c4y;
    float Cvz = 1.0f + 2.0f*(c2z + c3z) + c4z;
    float Cpx = c2x + c3x;
    float Cpy = c2y + c3y;
    float Cpz = 1.0f + c2z + c3z;

    float un   = sqrtf(P.x*P.x + P.y*P.y + P.z*P.z);
    float phih = atan2f(un, P.w);
    float ux, uy, uz;
    if (un > 1e-20f) { float iu = 1.0f/un; ux = P.x*iu; uy = P.y*iu; uz = P.z*iu; }
    else             { ux = 0.0f; uy = 0.0f; uz = 1.0f; }

    float dv = ux*Cvx + uy*Cvy + uz*Cvz;
    float vpx = dv*ux, vpy = dv*uy, vpz = dv*uz;
    float vex = Cvx - vpx, vey = Cvy - vpy, vez = Cvz - vpz;
    float vcx = uy*Cvz - uz*Cvy, vcy = uz*Cvx - ux*Cvz, vcz = ux*Cvy - uy*Cvx;
    float dp = ux*Cpx + uy*Cpy + uz*Cpz;
    float ppx = dp*ux, ppy = dp*uy, ppz = dp*uz;
    float pex = Cpx - ppx, pey = Cpy - ppy, pez = Cpz - ppz;
    float pcx = uy*Cpz - uz*Cpy, pcy = uz*Cpx - ux*Cpz, pcz = ux*Cpy - uy*Cpx;

    float qx = q0.x, qy = q0.y, qz = q0.z, qw = q0.w;
    float r00 = 1.0f - 2.0f*(qy*qy + qz*qz), r01 = 2.0f*(qx*qy - qw*qz), r02 = 2.0f*(qx*qz + qw*qy);
    float r10 = 2.0f*(qx*qy + qw*qz), r11 = 1.0f - 2.0f*(qx*qx + qz*qz), r12 = 2.0f*(qy*qz - qw*qx);
    float r20 = 2.0f*(qx*qz - qw*qy), r21 = 2.0f*(qy*qz + qw*qx), r22 = 1.0f - 2.0f*(qx*qx + qy*qy);
    #define ROT_X(X,Y,Z) (r00*(X) + r01*(Y) + r02*(Z))
    #define ROT_Y(X,Y,Z) (r10*(X) + r11*(Y) + r12*(Z))
    #define ROT_Z(X,Y,Z) (r20*(X) + r21*(Y) + r22*(Z))
    float Gvpx = ROT_X(vpx,vpy,vpz), Gvpy = ROT_Y(vpx,vpy,vpz), Gvpz = ROT_Z(vpx,vpy,vpz);
    float Gvex = ROT_X(vex,vey,vez), Gvey = ROT_Y(vex,vey,vez), Gvez = ROT_Z(vex,vey,vez);
    float Gvcx = ROT_X(vcx,vcy,vcz), Gvcy = ROT_Y(vcx,vcy,vcz), Gvcz = ROT_Z(vcx,vcy,vcz);
    float Gppx = ROT_X(ppx,ppy,ppz), Gppy = ROT_Y(ppx,ppy,ppz), Gppz = ROT_Z(ppx,ppy,ppz);
    float Gpex = ROT_X(pex,pey,pez), Gpey = ROT_Y(pex,pey,pez), Gpez = ROT_Z(pex,pey,pez);
    float Gpcx = ROT_X(pcx,pcy,pcz), Gpcy = ROT_Y(pcx,pcy,pcz), Gpcz = ROT_Z(pcx,pcy,pcz);

    // quat-power coefficients: qt = st*A + ct*q0 (componentwise), Aw = -(q0.u)
    float Ax = q0.w*ux + q0.y*uz - q0.z*uy;
    float Ay = q0.w*uy + q0.z*ux - q0.x*uz;
    float Az = q0.w*uz + q0.x*uy - q0.y*ux;
    float Aw = -(q0.x*ux + q0.y*uy + q0.z*uz);

    float4* w4 = (float4*)(ws + (size_t)env * CF);
    w4[0] = make_float4(Gvpx, Gvpy, Gvpz, Gvex);
    w4[1] = make_float4(Gvey, Gvez, Gvcx, Gvcy);
    w4[2] = make_float4(Gvcz, Gppx, Gppy, Gppz);
    w4[3] = make_float4(Gpex, Gpey, Gpez, Gpcx);
    w4[4] = make_float4(Gpcy, Gpcz, Ax,   Ay);
    w4[5] = make_float4(Az,   Aw,   phih, q0.x);
    w4[6] = make_float4(q0.y, q0.z, q0.w, vx0);
    w4[7] = make_float4(vy0,  vz0,  px0,  py0);
    w4[8] = make_float4(pz0,  ox,   oy,   oz);
}

// ---------------------------------------------------------------------------
// Kernel B: scan + emit with LDS-staged coalesced stores.
// One wave per env; N/128 passes of 128 rows (2 rows/lane); wave-private LDS.
// ---------------------------------------------------------------------------
__global__ __launch_bounds__(128, 6)
void quad_emit2_kernel(const float4* __restrict__ u_seq,
                       const float* __restrict__ ws,
                       float4* __restrict__ out4,
                       int B, int N)
{
    __shared__ float lds[2][1536];       // per-wave 128 rows x 12 floats
    const int wave = threadIdx.x >> 6;
    const int lane = threadIdx.x & 63;
    const int env  = blockIdx.x * 2 + wave;
    if (env >= B) return;
    const int npass = N >> 7;

    // u pointer pre-offset by this lane's first row; issue pass-0 loads early
    const float4* __restrict__ up = u_seq + (size_t)env * N + 2 * lane;
    float4 ua = up[0], ub = up[1];

    const float* __restrict__ c =
        ws + (size_t)__builtin_amdgcn_readfirstlane(env) * CF;
    float Gvpx = rfl(c[0]),  Gvpy = rfl(c[1]),  Gvpz = rfl(c[2]);
    float Gvex = rfl(c[3]),  Gvey = rfl(c[4]),  Gvez = rfl(c[5]);
    float Gvcx = rfl(c[6]),  Gvcy = rfl(c[7]),  Gvcz = rfl(c[8]);
    float Gppx = rfl(c[9]),  Gppy = rfl(c[10]), Gppz = rfl(c[11]);
    float Gpex = rfl(c[12]), Gpey = rfl(c[13]), Gpez = rfl(c[14]);
    float Gpcx = rfl(c[15]), Gpcy = rfl(c[16]), Gpcz = rfl(c[17]);
    __builtin_amdgcn_sched_barrier(0);   // split const batches (VGPR peak)
    float Ax = rfl(c[18]), Ay = rfl(c[19]), Az = rfl(c[20]), Aw = rfl(c[21]);
    float phih = rfl(c[22]);
    float q0x = rfl(c[23]), q0y = rfl(c[24]), q0z = rfl(c[25]), q0w = rfl(c[26]);
    float vx0 = rfl(c[27]), vy0 = rfl(c[28]), vz0 = rfl(c[29]);
    float px0 = rfl(c[30]), py0 = rfl(c[31]), pz0 = rfl(c[32]);
    float ox  = rfl(c[33]), oy  = rfl(c[34]), oz  = rfl(c[35]);
    const float theta = phih + phih;

    const float dt      = DT_;
    const float invTMAX = 1.0f / (TTW_ * M_ * G_);
    const float TACC    = TTW_ * G_;
    const float dt6     = dt * (1.0f/6.0f);
    const float dt26    = dt * dt * (1.0f/6.0f);
    const float gdt     = dt * G_;
    const float hgdt2   = 0.5f * dt * dt * G_;
    const float dtvx = dt*vx0, dtvy = dt*vy0, dtvz = dt*vz0;

    float ca=0.f, cb=0.f, cc=0.f, cA=0.f, cB=0.f, cC=0.f;   // scan carries
    float* __restrict__ lw = lds[wave];

    for (int p = 0; p < npass; ++p) {
        const float kf0 = (float)((p << 7) + 2 * lane);
        const float kf1 = kf0 + 1.0f;

        // thrust + trig for this pass's two rows
        float w2a = fmaf(ua.x,ua.x, fmaf(ua.y,ua.y, fmaf(ua.z,ua.z, ua.w*ua.w)));
        float Ta0 = fminf(fmaxf(KT_*w2a*invTMAX, 0.0f), 1.0f) * TACC;
        float w2b = fmaf(ub.x,ub.x, fmaf(ub.y,ub.y, fmaf(ub.z,ub.z, ub.w*ub.w)));
        float Ta1 = fminf(fmaxf(KT_*w2b*invTMAX, 0.0f), 1.0f) * TACC;
        float sn0, cs0; fsincos(theta * kf0, sn0, cs0);
        float sn1, cs1; fsincos(theta * kf1, sn1, cs1);
        float kT0 = kf0 * Ta0, kT1 = kf1 * Ta1;

        float sa = Ta0 + Ta1;
        float sb = fmaf(Ta0, cs0, Ta1 * cs1);
        float sc = fmaf(Ta0, sn0, Ta1 * sn1);
        float sA = kT0 + kT1;
        float sB = fmaf(kT0, cs0, kT1 * cs1);
        float sC = fmaf(kT0, sn0, kT1 * sn1);

        // wave-wide inclusive scan of lane totals
        float ta=sa, tb=sb, tc=sc, tA=sA, tB=sB, tC=sC;
        #pragma unroll
        for (int d = 1; d < 64; d <<= 1) {
            float xa = __shfl_up(ta, d), xb = __shfl_up(tb, d), xc = __shfl_up(tc, d);
            float xA = __shfl_up(tA, d), xB = __shfl_up(tB, d), xC = __shfl_up(tC, d);
            if (lane >= d) { ta += xa; tb += xb; tc += xc; tA += xA; tB += xB; tC += xC; }
        }
        // exclusive bases (+ carry from previous passes)
        float aa = ca + (ta - sa), ab = cb + (tb - sb), ac = cc + (tc - sc);
        float aA = cA + (tA - sA), aB = cB + (tB - sB), aC = cC + (tC - sC);
        ca += __shfl(ta, 63); cb += __shfl(tb, 63); cc += __shfl(tc, 63);
        cA += __shfl(tA, 63); cB += __shfl(tB, 63); cC += __shfl(tC, 63);

        // compute 2 rows -> LDS (chunk-rotation swizzle (c + row) % 3)
        #define ROW(J, TA, CS, SN, KF) { \
            aa += (TA); ab = fmaf((TA), (CS), ab); ac = fmaf((TA), (SN), ac); \
            float kTa = (KF) * (TA); \
            aA += kTa; aB = fmaf(kTa, (CS), aB); aC = fmaf(kTa, (SN), aC); \
            float tf = (KF) + 1.0f; \
            float Wa = fmaf((KF), aa, -aA), Wb = fmaf((KF), ab, -aB), Wc = fmaf((KF), ac, -aC); \
            float rvx = fmaf(aa, Gvpx, fmaf(ab, Gvex, ac*Gvcx)); \
            float rvy = fmaf(aa, Gvpy, fmaf(ab, Gvey, ac*Gvcy)); \
            float rvz = fmaf(aa, Gvpz, fmaf(ab, Gvez, ac*Gvcz)); \
            float rpx = fmaf(Wa, Gvpx, fmaf(Wb, Gvex, fmaf(Wc, Gvcx, fmaf(aa, Gppx, fmaf(ab, Gpex, ac*Gpcx))))); \
            float rpy = fmaf(Wa, Gvpy, fmaf(Wb, Gvey, fmaf(Wc, Gvcy, fmaf(aa, Gppy, fmaf(ab, Gpey, ac*Gpcy))))); \
            float rpz = fmaf(Wa, Gvpz, fmaf(Wb, Gvez, fmaf(Wc, Gvcz, fmaf(aa, Gppz, fmaf(ab, Gpez, ac*Gpcz))))); \
            float velx = fmaf(dt6, rvx, vx0); \
            float vely = fmaf(dt6, rvy, vy0); \
            float velz = fmaf(dt6, rvz, vz0) - tf * gdt; \
            float posx = fmaf(tf, dtvx, fmaf(dt26, rpx, px0)); \
            float posy = fmaf(tf, dtvy, fmaf(dt26, rpy, py0)); \
            float posz = fmaf(tf, dtvz, fmaf(dt26, rpz, pz0)) - (tf*tf) * hgdt2; \
            float st, ct; fsincos(phih * tf, st, ct); \
            float qtx = fmaf(st, Ax, ct * q0x); \
            float qty = fmaf(st, Ay, ct * q0y); \
            float qtz = fmaf(st, Az, ct * q0z); \
            float qtw = fmaf(st, Aw, ct * q0w); \
            float nv  = sqrtf(fmaf(qtx, qtx, fmaf(qty, qty, qtz*qtz))); \
            float h   = half_atan2_unit(nv, qtw); \
            float scl = (h + h) * frcp(fmaxf(nv, 1e-12f)); \
            int rr = 2 * lane + (J); \
            float4* bp = (float4*)&lw[rr * 12]; \
            int s0 = rr % 3; \
            int s1 = s0 + 1; if (s1 == 3) s1 = 0; \
            int s2 = s1 + 1; if (s2 == 3) s2 = 0; \
            bp[s0] = make_float4(posx, posy, posz, velx); \
            bp[s1] = make_float4(vely, velz, qtx*scl, qty*scl); \
            bp[s2] = make_float4(qtz*scl, ox, oy, oz); }
        ROW(0, Ta0, cs0, sn0, kf0)
        ROW(1, Ta1, cs1, sn1, kf1)
        #undef ROW

        // prefetch next pass's u before the flush (overlaps HBM latency)
        if (p + 1 < npass) {
            ua = up[(p + 1) << 7];
            ub = up[((p + 1) << 7) + 1];
        }

        // flush: 6 fully-coalesced dwordx4 stores (1 KB/instruction/wave)
        size_t ob = (size_t)env * (size_t)(3 * N) + (size_t)(p * 384);
        #pragma unroll
        for (int i = 0; i < 6; ++i) {
            int m  = (i << 6) + lane;        // float4 chunk index in half-tile
            int r  = m / 3;                  // logical row (magic div)
            int c3 = m - 3 * r;              // logical chunk in row
            int rm = r % 3;
            int cp = c3 + rm; if (cp >= 3) cp -= 3;   // stored position
            float4 v = *(const float4*)&lw[r * 12 + (cp << 2)];
            out4[ob + m] = v;
        }
    }
}

// ---------------------------------------------------------------------------
// Fallback: monolithic kernel (round-3, proven) if ws too small or N%128!=0.
// ---------------------------------------------------------------------------
__global__ __launch_bounds__(256)
void quad_mono_kernel(const float* __restrict__ x0,
                      const float4* __restrict__ u_seq,
                      float* __restrict__ out,
                      int B, int N)
{
    const int wave = threadIdx.x >> 6;
    const int lane = threadIdx.x & 63;
    const int env  = blockIdx.x * 4 + wave;
    if (env >= B) return;

    const float4* xs4 = (const float4*)(x0 + (size_t)env * 12);
    float4 xA = xs4[0], xB = xs4[1], xC = xs4[2];
    const float px0 = xA.x, py0 = xA.y, pz0 = xA.z;
    const float vx0 = xA.w, vy0 = xB.x, vz0 = xB.y;
    const float rx  = xB.z, ry  = xB.w, rz  = xC.x;
    const float ox  = xC.y, oy  = xC.z, oz  = xC.w;

    float ang = sqrtf(rx*rx + ry*ry + rz*rz);
    float hf  = 0.5f * ang;
    float sh, ch;
    sincosf(hf, &sh, &ch);
    float so = (ang < EPS_) ? (0.5f - ang*ang*(1.0f/48.0f)) : (sh / ang);
    float4 q0 = make_float4(rx*so, ry*so, rz*so, ch);

    const float dt = DT_, dt4 = 0.25f*dt, dt2 = 0.5f*dt, dt12 = dt*(1.0f/12.0f);
    float4 n2 = qnormalize(make_float4(dt4*ox, dt4*oy, dt4*oz, 1.0f));
    float4 m2 = qmul_pure(n2, ox, oy, oz);
    float4 n3 = qnormalize(make_float4(dt4*m2.x, dt4*m2.y, dt4*m2.z, 1.0f + dt4*m2.w));
    float4 m3 = qmul_pure(n3, ox, oy, oz);
    float4 n4 = qnormalize(make_float4(dt2*m3.x, dt2*m3.y, dt2*m3.z, 1.0f + dt2*m3.w));
    float4 m4 = qmul_pure(n4, ox, oy, oz);
    float4 P  = qnormalize(make_float4(
        dt12*(ox + 2.0f*m2.x + 2.0f*m3.x + m4.x),
        dt12*(oy + 2.0f*m2.y + 2.0f*m3.y + m4.y),
        dt12*(oz + 2.0f*m2.z + 2.0f*m3.z + m4.z),
        1.0f + dt12*(2.0f*m2.w + 2.0f*m3.w + m4.w)));

    float c2x = COL3X(n2), c2y = COL3Y(n2), c2z = COL3Z(n2);
    float c3x = COL3X(n3), c3y = COL3Y(n3), c3z = COL3Z(n3);
    float c4x = COL3X(n4), c4y = COL3Y(n4), c4z = COL3Z(n4);
    float Cvx = 2.0f*(c2x + c3x) + c4x;
    float Cvy = 2.0f*(c2y + c3y) + c4y;
    float Cvz = 1.0f + 2.0f*(c2z + c3z) + c4z;
    float Cpx = c2x + c3x;
    float Cpy = c2y + c3y;
    float Cpz = 1.0f + c2z + c3z;

    float un   = sqrtf(P.x*P.x + P.y*P.y + P.z*P.z);
    float phih = atan2f(un, P.w);
    float theta = 2.0f * phih;
    float ux, uy, uz;
    if (un > 1e-20f) { float iu = 1.0f/un; ux = P.x*iu; uy = P.y*iu; uz = P.z*iu; }
    else             { ux = 0.0f; uy = 0.0f; uz = 1.0f; }

    float dv = ux*Cvx + uy*Cvy + uz*Cvz;
    float vpx = dv*ux, vpy = dv*uy, vpz = dv*uz;
    float vex = Cvx - vpx, vey = Cvy - vpy, vez = Cvz - vpz;
    float vcx = uy*Cvz - uz*Cvy, vcy = uz*Cvx - ux*Cvz, vcz = ux*Cvy - uy*Cvx;
    float dp = ux*Cpx + uy*Cpy + uz*Cpz;
    float ppx = dp*ux, ppy = dp*uy, ppz = dp*uz;
    float pex = Cpx - ppx, pey = Cpy - ppy, pez = Cpz - ppz;
    float pcx = uy*Cpz - uz*Cpy, pcy = uz*Cpx - ux*Cpz, pcz = ux*Cpy - uy*Cpx;

    float qx = q0.x, qy = q0.y, qz = q0.z, qw = q0.w;
    float r00 = 1.0f - 2.0f*(qy*qy + qz*qz), r01 = 2.0f*(qx*qy - qw*qz), r02 = 2.0f*(qx*qz + qw*qy);
    float r10 = 2.0f*(qx*qy + qw*qz), r11 = 1.0f - 2.0f*(qx*qx + qz*qz), r12 = 2.0f*(qy*qz - qw*qx);
    float r20 = 2.0f*(qx*qz - qw*qy), r21 = 2.0f*(qy*qz + qw*qx), r22 = 1.0f - 2.0f*(qx*qx + qy*qy);
    float Gvpx = ROT_X(vpx,vpy,vpz), Gvpy = ROT_Y(vpx,vpy,vpz), Gvpz = ROT_Z(vpx,vpy,vpz);
    float Gvex = ROT_X(vex,vey,vez), Gvey = ROT_Y(vex,vey,vez), Gvez = ROT_Z(vex,vey,vez);
    float Gvcx = ROT_X(vcx,vcy,vcz), Gvcy = ROT_Y(vcx,vcy,vcz), Gvcz = ROT_Z(vcx,vcy,vcz);
    float Gppx = ROT_X(ppx,ppy,ppz), Gppy = ROT_Y(ppx,ppy,ppz), Gppz = ROT_Z(ppx,ppy,ppz);
    float Gpex = ROT_X(pex,pey,pez), Gpey = ROT_Y(pex,pey,pez), Gpez = ROT_Z(pex,pey,pez);
    float Gpcx = ROT_X(pcx,pcy,pcz), Gpcy = ROT_Y(pcx,pcy,pcz), Gpcz = ROT_Z(pcx,pcy,pcz);

    const float invTMAX = 1.0f / (TTW_ * M_ * G_);
    const float TACC    = TTW_ * G_;

    const float4* __restrict__ up = u_seq + (size_t)env * N;
    float la[4], lb[4], lc[4], lA[4], lB[4], lC[4];
    float sa = 0.f, sb = 0.f, sc = 0.f, sA = 0.f, sB = 0.f, sC = 0.f;
    const int k0 = lane * 4;
    #pragma unroll
    for (int j = 0; j < 4; ++j) {
        int k = k0 + j;
        float Ta = 0.f, cs = 1.f, sn = 0.f, kf = (float)k;
        if (k < N) {
            float4 u = up[k];
            float w2 = u.x*u.x + u.y*u.y + u.z*u.z + u.w*u.w;
            float Tn = fminf(fmaxf(KT_*w2*invTMAX, 0.0f), 1.0f);
            Ta = Tn * TACC;
            fsincos(theta * kf, sn, cs);
        }
        sa += Ta;        sb += Ta*cs;     sc += Ta*sn;
        sA += kf*Ta;     sB += kf*Ta*cs;  sC += kf*Ta*sn;
        la[j] = sa; lb[j] = sb; lc[j] = sc;
        lA[j] = sA; lB[j] = sB; lC[j] = sC;
    }

    float ta = sa, tb = sb, tc = sc, tA = sA, tB = sB, tC = sC;
    #pragma unroll
    for (int d = 1; d < 64; d <<= 1) {
        float xa = __shfl_up(ta, d), xb = __shfl_up(tb, d), xc = __shfl_up(tc, d);
        float xA = __shfl_up(tA, d), xB = __shfl_up(tB, d), xC = __shfl_up(tC, d);
        if (lane >= d) { ta += xa; tb += xb; tc += xc; tA += xA; tB += xB; tC += xC; }
    }
    const float ba = ta - sa, bb = tb - sb, bc = tc - sc;
    const float bA = tA - sA, bB = tB - sB, bC = tC - sC;

    float* __restrict__ op = out + (size_t)env * N * 12;
    const float dt6  = dt * (1.0f/6.0f);
    const float dt26 = dt * dt * (1.0f/6.0f);
    #pragma unroll
    for (int j = 0; j < 4; ++j) {
        int k = k0 + j;
        if (k >= N) break;
        float Ea = ba + la[j], Eb = bb + lb[j], Ec = bc + lc[j];
        float EA = bA + lA[j], EB = bB + lB[j], EC = bC + lC[j];
        float tf = (float)(k + 1);
        float cw = tf - 1.0f;
        float Wa = cw*Ea - EA, Wb = cw*Eb - EB, Wc = cw*Ec - EC;

        float rvx = Gvpx*Ea + Gvex*Eb + Gvcx*Ec;
        float rvy = Gvpy*Ea + Gvey*Eb + Gvcy*Ec;
        float rvz = Gvpz*Ea + Gvez*Eb + Gvcz*Ec;
        float rpx = Gvpx*Wa + Gvex*Wb + Gvcx*Wc + Gppx*Ea + Gpex*Eb + Gpcx*Ec;
        float rpy = Gvpy*Wa + Gvey*Wb + Gvcy*Wc + Gppy*Ea + Gpey*Eb + Gpcy*Ec;
        float rpz = Gvpz*Wa + Gvez*Wb + Gvcz*Wc + Gppz*Ea + Gpez*Eb + Gpcz*Ec;

        float velx = vx0 + dt6*rvx;
        float vely = vy0 + dt6*rvy;
        float velz = vz0 + dt6*rvz - tf*dt*G_;
        float posx = px0 + tf*dt*vx0 + dt26*rpx;
        float posy = py0 + tf*dt*vy0 + dt26*rpy;
        float posz = pz0 + tf*dt*vz0 + dt26*rpz - 0.5f*tf*tf*dt*dt*G_;

        float st, ct;
        fsincos(phih * tf, st, ct);
        float4 Pt = make_float4(ux*st, uy*st, uz*st, ct);
        float4 qt = qmul(q0, Pt);

        float nv  = sqrtf(qt.x*qt.x + qt.y*qt.y + qt.z*qt.z);
        float h   = half_atan2_unit(nv, qt.w);
        float scl = 2.0f * h / fmaxf(nv, 1e-12f);

        float4* o4 = (float4*)(op + (size_t)k * 12);
        o4[0] = make_float4(posx, posy, posz, velx);
        o4[1] = make_float4(vely, velz, qt.x*scl, qt.y*scl);
        o4[2] = make_float4(qt.z*scl, ox, oy, oz);
    }
}

extern "C" void kernel_launch(void* const* d_in, const int* in_sizes, int n_in,
                              void* d_out, int out_size, void* d_ws, size_t ws_size,
                              hipStream_t stream) {
    const float*  x0    = (const float*)d_in[0];
    const float4* u_seq = (const float4*)d_in[1];
    int B = in_sizes[0] / 12;
    int N = in_sizes[1] / (B * 4);
    size_t need = (size_t)B * CF * sizeof(float);
    if (ws_size >= need && (N & 127) == 0 && N >= 128) {
        float* ws = (float*)d_ws;
        hipLaunchKernelGGL(quad_prep_kernel, dim3((B + 255) / 256), dim3(256), 0, stream,
                           x0, ws, B);
        hipLaunchKernelGGL(quad_emit2_kernel, dim3((B + 1) / 2), dim3(128), 0, stream,
                           u_seq, ws, (float4*)d_out, B, N);
    } else {
        hipLaunchKernelGGL(quad_mono_kernel, dim3((B + 3) / 4), dim3(256), 0, stream,
                           x0, u_seq, (float*)d_out, B, N);
    }
}

// Round 6
// 50.700 us; speedup vs baseline: 2.0737x; 1.4719x over previous
//
#include <hip/hip_runtime.h>
#include <math.h>

// PhysQuadModel rollout, fully parallel over (env, time).
// Round-6: single kernel (prep inlined, no libm, no ws round-trip);
// even/odd LDS slot map makes ds_write_b128 bank-conflict-free
// (lane stride 48B -> start banks 12l%32 cover all 32 banks per 8 lanes);
// nontemporal u loads. Flush stores stay fully coalesced (1KB/instr).

namespace {
constexpr float DT_  = 0.01f;
constexpr float G_   = 9.81f;
constexpr float TTW_ = 1.8f;
constexpr float M_   = 0.033f;
constexpr float KT_  = 3.72e-08f;
constexpr float EPS_ = 1e-6f;
constexpr float INV2PI = 0.15915494309189535f;
constexpr float PI_F   = 3.14159265358979f;
constexpr float PIH_F  = 1.57079632679490f;
}

using vf4 = __attribute__((ext_vector_type(4))) float;

__device__ __forceinline__ void fsincos(float x, float& s, float& c) {
#if __has_builtin(__builtin_amdgcn_sinf) && __has_builtin(__builtin_amdgcn_cosf)
    float r = x * INV2PI;
    r = r - floorf(r);              // v_fract; v_sin/v_cos take revolutions
    s = __builtin_amdgcn_sinf(r);
    c = __builtin_amdgcn_cosf(r);
#else
    s = sinf(x); c = cosf(x);
#endif
}

__device__ __forceinline__ float frcp(float x) {
#if __has_builtin(__builtin_amdgcn_rcpf)
    return __builtin_amdgcn_rcpf(x);
#else
    return 1.0f / x;
#endif
}

// refined reciprocal (~0.5 ulp)
__device__ __forceinline__ float rcp_nr(float x) {
    float r = frcp(x);
    return r * (2.0f - x * r);
}

__device__ __forceinline__ float rfl(float x) {
    return __int_as_float(__builtin_amdgcn_readfirstlane(__float_as_int(x)));
}

// atan2(nv, qw) for nv >= 0 with nv^2 + qw^2 == 1 (unit circle). No division.
__device__ __forceinline__ float half_atan2_unit(float nv, float qw) {
    float aw = fabsf(qw);
    float m  = fminf(nv, aw);
    float t  = m * m;
    float p  = 0.01155185f;
    p = fmaf(p, t, 0.01396482f);
    p = fmaf(p, t, 0.01735277f);
    p = fmaf(p, t, 0.02237216f);
    p = fmaf(p, t, 0.03038194f);
    p = fmaf(p, t, 0.04464286f);
    p = fmaf(p, t, 0.075f);
    p = fmaf(p, t, 0.16666667f);
    p = fmaf(p, t, 1.0f);
    p = p * m;                                  // asin(m)
    return (nv < aw) ? ((qw >= 0.0f) ? p : (PI_F - p))
                     : (PIH_F - copysignf(p, qw));
}

__device__ __forceinline__ float4 qmul(float4 p, float4 q) {
    return make_float4(
        p.w*q.x + q.w*p.x + (p.y*q.z - p.z*q.y),
        p.w*q.y + q.w*p.y + (p.z*q.x - p.x*q.z),
        p.w*q.z + q.w*p.z + (p.x*q.y - p.y*q.x),
        p.w*q.w - (p.x*q.x + p.y*q.y + p.z*q.z));
}

__device__ __forceinline__ float4 qnormalize(float4 q) {
    float inv = 1.0f / sqrtf(q.x*q.x + q.y*q.y + q.z*q.z + q.w*q.w);
    return make_float4(q.x*inv, q.y*inv, q.z*inv, q.w*inv);
}

__device__ __forceinline__ float4 qmul_pure(float4 n, float wx, float wy, float wz) {
    return make_float4(
        n.w*wx + (n.y*wz - n.z*wy),
        n.w*wy + (n.z*wx - n.x*wz),
        n.w*wz + (n.x*wy - n.y*wx),
        -(n.x*wx + n.y*wy + n.z*wz));
}

#define COL3X(q) (2.0f*((q).x*(q).z + (q).w*(q).y))
#define COL3Y(q) (2.0f*((q).y*(q).z - (q).w*(q).x))
#define COL3Z(q) (1.0f - 2.0f*((q).x*(q).x + (q).y*(q).y))
#define ROT_X(X,Y,Z) (r00*(X) + r01*(Y) + r02*(Z))
#define ROT_Y(X,Y,Z) (r10*(X) + r11*(Y) + r12*(Z))
#define ROT_Z(X,Y,Z) (r20*(X) + r21*(Y) + r22*(Z))

// ---------------------------------------------------------------------------
// Single fused kernel: inline prep (all-lane redundant, libm-free) +
// scan/emit with LDS-staged coalesced stores. One wave per env.
// ---------------------------------------------------------------------------
__global__ __launch_bounds__(128)
void quad_fused_kernel(const float* __restrict__ x0,
                       const vf4* __restrict__ u_seq,
                       vf4* __restrict__ out4,
                       int B, int N)
{
    __shared__ float lds[2][1536];       // per-wave 128 slots x 12 floats
    const int wave = threadIdx.x >> 6;
    const int lane = threadIdx.x & 63;
    const int env  = blockIdx.x * 2 + wave;
    if (env >= B) return;
    const int npass = N >> 7;

    // issue pass-0 u loads first; HBM latency hides under inline prep
    const vf4* __restrict__ up = u_seq + (size_t)env * N + 2 * lane;
    vf4 ua = __builtin_nontemporal_load(up);
    vf4 ub = __builtin_nontemporal_load(up + 1);

    // -------- inline prep (redundant across lanes; temps die at rfl) --------
    float Gvpx, Gvpy, Gvpz, Gvex, Gvey, Gvez, Gvcx, Gvcy, Gvcz;
    float Gppx, Gppy, Gppz, Gpex, Gpey, Gpez, Gpcx, Gpcy, Gpcz;
    float Ax, Ay, Az, Aw, phih, q0x, q0y, q0z, q0w;
    float vx0, vy0, vz0, px0, py0, pz0, ox, oy, oz;
    {
        const float4* xs4 = (const float4*)(x0 + (size_t)env * 12);
        float4 xA = xs4[0], xB = xs4[1], xC = xs4[2];
        float px_ = xA.x, py_ = xA.y, pz_ = xA.z;
        float vx_ = xA.w, vy_ = xB.x, vz_ = xB.y;
        float rx  = xB.z, ry  = xB.w, rz  = xC.x;
        float ox_ = xC.y, oy_ = xC.z, oz_ = xC.w;

        float ang = sqrtf(rx*rx + ry*ry + rz*rz);
        float hf  = 0.5f * ang;
        float sh, ch;
        fsincos(hf, sh, ch);
        float so = (ang < EPS_) ? (0.5f - ang*ang*(1.0f/48.0f)) : (sh * rcp_nr(ang));
        float4 q0 = make_float4(rx*so, ry*so, rz*so, ch);

        const float dt = DT_, dt4 = 0.25f*dt, dt2 = 0.5f*dt, dt12 = dt*(1.0f/12.0f);
        float4 n2 = qnormalize(make_float4(dt4*ox_, dt4*oy_, dt4*oz_, 1.0f));
        float4 m2 = qmul_pure(n2, ox_, oy_, oz_);
        float4 n3 = qnormalize(make_float4(dt4*m2.x, dt4*m2.y, dt4*m2.z, 1.0f + dt4*m2.w));
        float4 m3 = qmul_pure(n3, ox_, oy_, oz_);
        float4 n4 = qnormalize(make_float4(dt2*m3.x, dt2*m3.y, dt2*m3.z, 1.0f + dt2*m3.w));
        float4 m4 = qmul_pure(n4, ox_, oy_, oz_);
        float4 P  = qnormalize(make_float4(
            dt12*(ox_ + 2.0f*m2.x + 2.0f*m3.x + m4.x),
            dt12*(oy_ + 2.0f*m2.y + 2.0f*m3.y + m4.y),
            dt12*(oz_ + 2.0f*m2.z + 2.0f*m3.z + m4.z),
            1.0f + dt12*(2.0f*m2.w + 2.0f*m3.w + m4.w)));

        float c2x = COL3X(n2), c2y = COL3Y(n2), c2z = COL3Z(n2);
        float c3x = COL3X(n3), c3y = COL3Y(n3), c3z = COL3Z(n3);
        float c4x = COL3X(n4), c4y = COL3Y(n4), c4z = COL3Z(n4);
        float Cvx = 2.0f*(c2x + c3x) + c4x;
        float Cvy = 2.0f*(c2y + c3y) + c4y;
        float Cvz = 1.0f + 2.0f*(c2z + c3z) + c4z;
        float Cpx = c2x + c3x;
        float Cpy = c2y + c3y;
        float Cpz = 1.0f + c2z + c3z;

        float un = sqrtf(P.x*P.x + P.y*P.y + P.z*P.z);
        // phih = atan2(un, P.w); P.w ~= 1, un/P.w < 0.05 -> 4-term atan poly
        {
            float xr = un * rcp_nr(P.w);
            float t2 = xr * xr;
            float pp = -1.0f/7.0f;
            pp = fmaf(pp, t2, 0.2f);
            pp = fmaf(pp, t2, -1.0f/3.0f);
            pp = pp * t2;
            phih = fmaf(pp, xr, xr);
        }
        float ux, uy, uz;
        if (un > 1e-20f) { float iu = rcp_nr(un); ux = P.x*iu; uy = P.y*iu; uz = P.z*iu; }
        else             { ux = 0.0f; uy = 0.0f; uz = 1.0f; }

        float dv = ux*Cvx + uy*Cvy + uz*Cvz;
        float vpx = dv*ux, vpy = dv*uy, vpz = dv*uz;
        float vex = Cvx - vpx, vey = Cvy - vpy, vez = Cvz - vpz;
        float vcx = uy*Cvz - uz*Cvy, vcy = uz*Cvx - ux*Cvz, vcz = ux*Cvy - uy*Cvx;
        float dp = ux*Cpx + uy*Cpy + uz*Cpz;
        float ppx = dp*ux, ppy = dp*uy, ppz = dp*uz;
        float pex = Cpx - ppx, pey = Cpy - ppy, pez = Cpz - ppz;
        float pcx = uy*Cpz - uz*Cpy, pcy = uz*Cpx - ux*Cpz, pcz = ux*Cpy - uy*Cpx;

        float qx = q0.x, qy = q0.y, qz = q0.z, qw = q0.w;
        float r00 = 1.0f - 2.0f*(qy*qy + qz*qz), r01 = 2.0f*(qx*qy - qw*qz), r02 = 2.0f*(qx*qz + qw*qy);
        float r10 = 2.0f*(qx*qy + qw*qz), r11 = 1.0f - 2.0f*(qx*qx + qz*qz), r12 = 2.0f*(qy*qz - qw*qx);
        float r20 = 2.0f*(qx*qz - qw*qy), r21 = 2.0f*(qy*qz + qw*qx), r22 = 1.0f - 2.0f*(qx*qx + qy*qy);

        Gvpx = rfl(ROT_X(vpx,vpy,vpz)); Gvpy = rfl(ROT_Y(vpx,vpy,vpz)); Gvpz = rfl(ROT_Z(vpx,vpy,vpz));
        Gvex = rfl(ROT_X(vex,vey,vez)); Gvey = rfl(ROT_Y(vex,vey,vez)); Gvez = rfl(ROT_Z(vex,vey,vez));
        Gvcx = rfl(ROT_X(vcx,vcy,vcz)); Gvcy = rfl(ROT_Y(vcx,vcy,vcz)); Gvcz = rfl(ROT_Z(vcx,vcy,vcz));
        Gppx = rfl(ROT_X(ppx,ppy,ppz)); Gppy = rfl(ROT_Y(ppx,ppy,ppz)); Gppz = rfl(ROT_Z(ppx,ppy,ppz));
        Gpex = rfl(ROT_X(pex,pey,pez)); Gpey = rfl(ROT_Y(pex,pey,pez)); Gpez = rfl(ROT_Z(pex,pey,pez));
        Gpcx = rfl(ROT_X(pcx,pcy,pcz)); Gpcy = rfl(ROT_Y(pcx,pcy,pcz)); Gpcz = rfl(ROT_Z(pcx,pcy,pcz));

        Ax = rfl(q0.w*ux + q0.y*uz - q0.z*uy);
        Ay = rfl(q0.w*uy + q0.z*ux - q0.x*uz);
        Az = rfl(q0.w*uz + q0.x*uy - q0.y*ux);
        Aw = rfl(-(q0.x*ux + q0.y*uy + q0.z*uz));
        phih = rfl(phih);
        q0x = rfl(q0.x); q0y = rfl(q0.y); q0z = rfl(q0.z); q0w = rfl(q0.w);
        vx0 = rfl(vx_); vy0 = rfl(vy_); vz0 = rfl(vz_);
        px0 = rfl(px_); py0 = rfl(py_); pz0 = rfl(pz_);
        ox = rfl(ox_); oy = rfl(oy_); oz = rfl(oz_);
    }
    const float theta = phih + phih;

    const float dt      = DT_;
    const float invTMAX = 1.0f / (TTW_ * M_ * G_);
    const float TACC    = TTW_ * G_;
    const float dt6     = dt * (1.0f/6.0f);
    const float dt26    = dt * dt * (1.0f/6.0f);
    const float gdt     = dt * G_;
    const float hgdt2   = 0.5f * dt * dt * G_;
    const float dtvx = dt*vx0, dtvy = dt*vy0, dtvz = dt*vz0;

    float ca=0.f, cb=0.f, cc=0.f, cA=0.f, cB=0.f, cC=0.f;   // scan carries
    float* __restrict__ lw = lds[wave];

    for (int p = 0; p < npass; ++p) {
        const float kf0 = (float)((p << 7) + 2 * lane);
        const float kf1 = kf0 + 1.0f;

        // thrust + trig for this pass's two rows
        float w2a = fmaf(ua.x,ua.x, fmaf(ua.y,ua.y, fmaf(ua.z,ua.z, ua.w*ua.w)));
        float Ta0 = fminf(fmaxf(KT_*w2a*invTMAX, 0.0f), 1.0f) * TACC;
        float w2b = fmaf(ub.x,ub.x, fmaf(ub.y,ub.y, fmaf(ub.z,ub.z, ub.w*ub.w)));
        float Ta1 = fminf(fmaxf(KT_*w2b*invTMAX, 0.0f), 1.0f) * TACC;
        float sn0, cs0; fsincos(theta * kf0, sn0, cs0);
        float sn1, cs1; fsincos(theta * kf1, sn1, cs1);
        float kT0 = kf0 * Ta0, kT1 = kf1 * Ta1;

        float sa = Ta0 + Ta1;
        float sb = fmaf(Ta0, cs0, Ta1 * cs1);
        float sc = fmaf(Ta0, sn0, Ta1 * sn1);
        float sA = kT0 + kT1;
        float sB = fmaf(kT0, cs0, kT1 * cs1);
        float sC = fmaf(kT0, sn0, kT1 * sn1);

        // wave-wide inclusive scan of lane totals
        float ta=sa, tb=sb, tc=sc, tA=sA, tB=sB, tC=sC;
        #pragma unroll
        for (int d = 1; d < 64; d <<= 1) {
            float xa = __shfl_up(ta, d), xb = __shfl_up(tb, d), xc = __shfl_up(tc, d);
            float xA = __shfl_up(tA, d), xB = __shfl_up(tB, d), xC = __shfl_up(tC, d);
            if (lane >= d) { ta += xa; tb += xb; tc += xc; tA += xA; tB += xB; tC += xC; }
        }
        // exclusive bases (+ carry from previous passes)
        float aa = ca + (ta - sa), ab = cb + (tb - sb), ac = cc + (tc - sc);
        float aA = cA + (tA - sA), aB = cB + (tB - sB), aC = cC + (tC - sC);
        ca += __shfl(ta, 63); cb += __shfl(tb, 63); cc += __shfl(tc, 63);
        cA += __shfl(tA, 63); cB += __shfl(tB, 63); cC += __shfl(tC, 63);

        // compute 2 rows -> LDS; even/odd slot map: row 2l -> slot l,
        // row 2l+1 -> slot 64+l (write lane-stride 48B: conflict-free)
        #define ROW(J, TA, CS, SN, KF) { \
            aa += (TA); ab = fmaf((TA), (CS), ab); ac = fmaf((TA), (SN), ac); \
            float kTa = (KF) * (TA); \
            aA += kTa; aB = fmaf(kTa, (CS), aB); aC = fmaf(kTa, (SN), aC); \
            float tf = (KF) + 1.0f; \
            float Wa = fmaf((KF), aa, -aA), Wb = fmaf((KF), ab, -aB), Wc = fmaf((KF), ac, -aC); \
            float rvx = fmaf(aa, Gvpx, fmaf(ab, Gvex, ac*Gvcx)); \
            float rvy = fmaf(aa, Gvpy, fmaf(ab, Gvey, ac*Gvcy)); \
            float rvz = fmaf(aa, Gvpz, fmaf(ab, Gvez, ac*Gvcz)); \
            float rpx = fmaf(Wa, Gvpx, fmaf(Wb, Gvex, fmaf(Wc, Gvcx, fmaf(aa, Gppx, fmaf(ab, Gpex, ac*Gpcx))))); \
            float rpy = fmaf(Wa, Gvpy, fmaf(Wb, Gvey, fmaf(Wc, Gvcy, fmaf(aa, Gppy, fmaf(ab, Gpey, ac*Gpcy))))); \
            float rpz = fmaf(Wa, Gvpz, fmaf(Wb, Gvez, fmaf(Wc, Gvcz, fmaf(aa, Gppz, fmaf(ab, Gpez, ac*Gpcz))))); \
            float velx = fmaf(dt6, rvx, vx0); \
            float vely = fmaf(dt6, rvy, vy0); \
            float velz = fmaf(dt6, rvz, vz0) - tf * gdt; \
            float posx = fmaf(tf, dtvx, fmaf(dt26, rpx, px0)); \
            float posy = fmaf(tf, dtvy, fmaf(dt26, rpy, py0)); \
            float posz = fmaf(tf, dtvz, fmaf(dt26, rpz, pz0)) - (tf*tf) * hgdt2; \
            float st, ct; fsincos(phih * tf, st, ct); \
            float qtx = fmaf(st, Ax, ct * q0x); \
            float qty = fmaf(st, Ay, ct * q0y); \
            float qtz = fmaf(st, Az, ct * q0z); \
            float qtw = fmaf(st, Aw, ct * q0w); \
            float nv  = sqrtf(fmaf(qtx, qtx, fmaf(qty, qty, qtz*qtz))); \
            float h   = half_atan2_unit(nv, qtw); \
            float scl = (h + h) * frcp(fmaxf(nv, 1e-12f)); \
            int slot = lane + ((J) << 6); \
            vf4* bp = (vf4*)&lw[slot * 12]; \
            bp[0] = (vf4){posx, posy, posz, velx}; \
            bp[1] = (vf4){vely, velz, qtx*scl, qty*scl}; \
            bp[2] = (vf4){qtz*scl, ox, oy, oz}; }
        ROW(0, Ta0, cs0, sn0, kf0)
        ROW(1, Ta1, cs1, sn1, kf1)
        #undef ROW

        // prefetch next pass's u before the flush (overlaps HBM latency)
        if (p + 1 < npass) {
            ua = __builtin_nontemporal_load(up + ((p + 1) << 7));
            ub = __builtin_nontemporal_load(up + ((p + 1) << 7) + 1);
        }

        // flush: 6 fully-coalesced dwordx4 stores (1 KB/instruction/wave)
        size_t ob = (size_t)env * (size_t)(3 * N) + (size_t)(p * 384);
        #pragma unroll
        for (int i = 0; i < 6; ++i) {
            int m  = (i << 6) + lane;        // float4 chunk index in half-tile
            int r  = m / 3;                  // logical row
            int c3 = m - 3 * r;              // chunk in row
            int slot = ((r & 1) << 6) | (r >> 1);
            vf4 v = *(const vf4*)&lw[slot * 12 + (c3 << 2)];
            out4[ob + m] = v;
        }
    }
}

// ---------------------------------------------------------------------------
// Fallback: monolithic kernel (round-3, proven) for odd shapes.
// ---------------------------------------------------------------------------
__global__ __launch_bounds__(256)
void quad_mono_kernel(const float* __restrict__ x0,
                      const float4* __restrict__ u_seq,
                      float* __restrict__ out,
                      int B, int N)
{
    const int wave = threadIdx.x >> 6;
    const int lane = threadIdx.x & 63;
    const int env  = blockIdx.x * 4 + wave;
    if (env >= B) return;

    const float4* xs4 = (const float4*)(x0 + (size_t)env * 12);
    float4 xA = xs4[0], xB = xs4[1], xC = xs4[2];
    const float px0 = xA.x, py0 = xA.y, pz0 = xA.z;
    const float vx0 = xA.w, vy0 = xB.x, vz0 = xB.y;
    const float rx  = xB.z, ry  = xB.w, rz  = xC.x;
    const float ox  = xC.y, oy  = xC.z, oz  = xC.w;

    float ang = sqrtf(rx*rx + ry*ry + rz*rz);
    float hf  = 0.5f * ang;
    float sh, ch;
    sincosf(hf, &sh, &ch);
    float so = (ang < EPS_) ? (0.5f - ang*ang*(1.0f/48.0f)) : (sh / ang);
    float4 q0 = make_float4(rx*so, ry*so, rz*so, ch);

    const float dt = DT_, dt4 = 0.25f*dt, dt2 = 0.5f*dt, dt12 = dt*(1.0f/12.0f);
    float4 n2 = qnormalize(make_float4(dt4*ox, dt4*oy, dt4*oz, 1.0f));
    float4 m2 = qmul_pure(n2, ox, oy, oz);
    float4 n3 = qnormalize(make_float4(dt4*m2.x, dt4*m2.y, dt4*m2.z, 1.0f + dt4*m2.w));
    float4 m3 = qmul_pure(n3, ox, oy, oz);
    float4 n4 = qnormalize(make_float4(dt2*m3.x, dt2*m3.y, dt2*m3.z, 1.0f + dt2*m3.w));
    float4 m4 = qmul_pure(n4, ox, oy, oz);
    float4 P  = qnormalize(make_float4(
        dt12*(ox + 2.0f*m2.x + 2.0f*m3.x + m4.x),
        dt12*(oy + 2.0f*m2.y + 2.0f*m3.y + m4.y),
        dt12*(oz + 2.0f*m2.z + 2.0f*m3.z + m4.z),
        1.0f + dt12*(2.0f*m2.w + 2.0f*m3.w + m4.w)));

    float c2x = COL3X(n2), c2y = COL3Y(n2), c2z = COL3Z(n2);
    float c3x = COL3X(n3), c3y = COL3Y(n3), c3z = COL3Z(n3);
    float c4x = COL3X(n4), c4y = COL3Y(n4), c4z = COL3Z(n4);
    float Cvx = 2.0f*(c2x + c3x) + c4x;
    float Cvy = 2.0f*(c2y + c3y) + c4y;
    float Cvz = 1.0f + 2.0f*(c2z + c3z) + c4z;
    float Cpx = c2x + c3x;
    float Cpy = c2y + c3y;
    float Cpz = 1.0f + c2z + c3z;

    float un   = sqrtf(P.x*P.x + P.y*P.y + P.z*P.z);
    float phih = atan2f(un, P.w);
    float theta = 2.0f * phih;
    float ux, uy, uz;
    if (un > 1e-20f) { float iu = 1.0f/un; ux = P.x*iu; uy = P.y*iu; uz = P.z*iu; }
    else             { ux = 0.0f; uy = 0.0f; uz = 1.0f; }

    float dv = ux*Cvx + uy*Cvy + uz*Cvz;
    float vpx = dv*ux, vpy = dv*uy, vpz = dv*uz;
    float vex = Cvx - vpx, vey = Cvy - vpy, vez = Cvz - vpz;
    float vcx = uy*Cvz - uz*Cvy, vcy = uz*Cvx - ux*Cvz, vcz = ux*Cvy - uy*Cvx;
    float dp = ux*Cpx + uy*Cpy + uz*Cpz;
    float ppx = dp*ux, ppy = dp*uy, ppz = dp*uz;
    float pex = Cpx - ppx, pey = Cpy - ppy, pez = Cpz - ppz;
    float pcx = uy*Cpz - uz*Cpy, pcy = uz*Cpx - ux*Cpz, pcz = ux*Cpy - uy*Cpx;

    float qx = q0.x, qy = q0.y, qz = q0.z, qw = q0.w;
    float r00 = 1.0f - 2.0f*(qy*qy + qz*qz), r01 = 2.0f*(qx*qy - qw*qz), r02 = 2.0f*(qx*qz + qw*qy);
    float r10 = 2.0f*(qx*qy + qw*qz), r11 = 1.0f - 2.0f*(qx*qx + qz*qz), r12 = 2.0f*(qy*qz - qw*qx);
    float r20 = 2.0f*(qx*qz - qw*qy), r21 = 2.0f*(qy*qz + qw*qx), r22 = 1.0f - 2.0f*(qx*qx + qy*qy);
    float Gvpx = ROT_X(vpx,vpy,vpz), Gvpy = ROT_Y(vpx,vpy,vpz), Gvpz = ROT_Z(vpx,vpy,vpz);
    float Gvex = ROT_X(vex,vey,vez), Gvey = ROT_Y(vex,vey,vez), Gvez = ROT_Z(vex,vey,vez);
    float Gvcx = ROT_X(vcx,vcy,vcz), Gvcy = ROT_Y(vcx,vcy,vcz), Gvcz = ROT_Z(vcx,vcy,vcz);
    float Gppx = ROT_X(ppx,ppy,ppz), Gppy = ROT_Y(ppx,ppy,ppz), Gppz = ROT_Z(ppx,ppy,ppz);
    float Gpex = ROT_X(pex,pey,pez), Gpey = ROT_Y(pex,pey,pez), Gpez = ROT_Z(pex,pey,pez);
    float Gpcx = ROT_X(pcx,pcy,pcz), Gpcy = ROT_Y(pcx,pcy,pcz), Gpcz = ROT_Z(pcx,pcy,pcz);

    const float invTMAX = 1.0f / (TTW_ * M_ * G_);
    const float TACC    = TTW_ * G_;

    const float4* __restrict__ up = u_seq + (size_t)env * N;
    float la[4], lb[4], lc[4], lA[4], lB[4], lC[4];
    float sa = 0.f, sb = 0.f, sc = 0.f, sA = 0.f, sB = 0.f, sC = 0.f;
    const int k0 = lane * 4;
    #pragma unroll
    for (int j = 0; j < 4; ++j) {
        int k = k0 + j;
        float Ta = 0.f, cs = 1.f, sn = 0.f, kf = (float)k;
        if (k < N) {
            float4 u = up[k];
            float w2 = u.x*u.x + u.y*u.y + u.z*u.z + u.w*u.w;
            float Tn = fminf(fmaxf(KT_*w2*invTMAX, 0.0f), 1.0f);
            Ta = Tn * TACC;
            fsincos(theta * kf, sn, cs);
        }
        sa += Ta;        sb += Ta*cs;     sc += Ta*sn;
        sA += kf*Ta;     sB += kf*Ta*cs;  sC += kf*Ta*sn;
        la[j] = sa; lb[j] = sb; lc[j] = sc;
        lA[j] = sA; lB[j] = sB; lC[j] = sC;
    }

    float ta = sa, tb = sb, tc = sc, tA = sA, tB = sB, tC = sC;
    #pragma unroll
    for (int d = 1; d < 64; d <<= 1) {
        float xa = __shfl_up(ta, d), xb = __shfl_up(tb, d), xc = __shfl_up(tc, d);
        float xA = __shfl_up(tA, d), xB = __shfl_up(tB, d), xC = __shfl_up(tC, d);
        if (lane >= d) { ta += xa; tb += xb; tc += xc; tA += xA; tB += xB; tC += xC; }
    }
    const float ba = ta - sa, bb = tb - sb, bc = tc - sc;
    const float bA = tA - sA, bB = tB - sB, bC = tC - sC;

    float* __restrict__ op = out + (size_t)env * N * 12;
    const float dt6  = dt * (1.0f/6.0f);
    const float dt26 = dt * dt * (1.0f/6.0f);
    #pragma unroll
    for (int j = 0; j < 4; ++j) {
        int k = k0 + j;
        if (k >= N) break;
        float Ea = ba + la[j], Eb = bb + lb[j], Ec = bc + lc[j];
        float EA = bA + lA[j], EB = bB + lB[j], EC = bC + lC[j];
        float tf = (float)(k + 1);
        float cw = tf - 1.0f;
        float Wa = cw*Ea - EA, Wb = cw*Eb - EB, Wc = cw*Ec - EC;

        float rvx = Gvpx*Ea + Gvex*Eb + Gvcx*Ec;
        float rvy = Gvpy*Ea + Gvey*Eb + Gvcy*Ec;
        float rvz = Gvpz*Ea + Gvez*Eb + Gvcz*Ec;
        float rpx = Gvpx*Wa + Gvex*Wb + Gvcx*Wc + Gppx*Ea + Gpex*Eb + Gpcx*Ec;
        float rpy = Gvpy*Wa + Gvey*Wb + Gvcy*Wc + Gppy*Ea + Gpey*Eb + Gpcy*Ec;
        float rpz = Gvpz*Wa + Gvez*Wb + Gvcz*Wc + Gppz*Ea + Gpez*Eb + Gpcz*Ec;

        float velx = vx0 + dt6*rvx;
        float vely = vy0 + dt6*rvy;
        float velz = vz0 + dt6*rvz - tf*dt*G_;
        float posx = px0 + tf*dt*vx0 + dt26*rpx;
        float posy = py0 + tf*dt*vy0 + dt26*rpy;
        float posz = pz0 + tf*dt*vz0 + dt26*rpz - 0.5f*tf*tf*dt*dt*G_;

        float st, ct;
        fsincos(phih * tf, st, ct);
        float4 Pt = make_float4(ux*st, uy*st, uz*st, ct);
        float4 qt = qmul(q0, Pt);

        float nv  = sqrtf(qt.x*qt.x + qt.y*qt.y + qt.z*qt.z);
        float h   = half_atan2_unit(nv, qt.w);
        float scl = 2.0f * h / fmaxf(nv, 1e-12f);

        float4* o4 = (float4*)(op + (size_t)k * 12);
        o4[0] = make_float4(posx, posy, posz, velx);
        o4[1] = make_float4(vely, velz, qt.x*scl, qt.y*scl);
        o4[2] = make_float4(qt.z*scl, ox, oy, oz);
    }
}

extern "C" void kernel_launch(void* const* d_in, const int* in_sizes, int n_in,
                              void* d_out, int out_size, void* d_ws, size_t ws_size,
                              hipStream_t stream) {
    const float* x0 = (const float*)d_in[0];
    int B = in_sizes[0] / 12;
    int N = in_sizes[1] / (B * 4);
    if ((N & 127) == 0 && N >= 128) {
        hipLaunchKernelGGL(quad_fused_kernel, dim3((B + 1) / 2), dim3(128), 0, stream,
                           x0, (const vf4*)d_in[1], (vf4*)d_out, B, N);
    } else {
        hipLaunchKernelGGL(quad_mono_kernel, dim3((B + 3) / 4), dim3(256), 0, stream,
                           x0, (const float4*)d_in[1], (float*)d_out, B, N);
    }
}